// Round 4
// baseline (434.281 us; speedup 1.0000x reference)
//
#include <hip/hip_runtime.h>

// SpikeLoss: loss = 0.5 * sum((outputs - psp(target))^2)
// psp: syn_t = syn_{t-1}*0.8 + x_t, emit syn_t/5   (tau=5)
// Shape [B=16, C=128, H=16, W=16, T=100], T contiguous. 524288 neurons.
//
// R9: R5/R6/R8 all pin at ~132us (3.2 TB/s delivered: 210MB HBM + 210MB
// L3-resident per dispatch) across wildly different schedules; occupancy
// 14%->52% changed nothing; VALU 7%, conflicts 0, writes negligible
// (WRITE_SIZE is KB -- earlier MB reading was a units error). The one
// invariant: every byte staged via global_load_lds DMA. R9 isolates that
// variable: identical structure/math/LDS-layout to R8, but staging is
// plain global_load_dwordx4 -> VGPR -> ds_write. outputs loads issue
// before the Phase-B barrier so HBM latency hides under E-scan + barrier;
// compiler's per-register vmcnt waits pipeline ds_writes against returns.
// Math (fma chains, compose order, reduce tree, partial layout) is
// bit-identical to R5/R8 -> absmax 0.0 preserved.
// LDS 25.7KB -> 6 blocks/CU. VGPR peak ~70 < 85 cap (launch_bounds 256,6).

#define T_STEPS 100
#define SEG 25
#define NPB 64                           // neurons per block
#define BLOCK 256
#define N_NEURONS (16 * 128 * 16 * 16)   // 524288
#define GRID_P (N_NEURONS / NPB)         // 8192 blocks
#define NPARTS GRID_P                    // one partial per 64-neuron block
#define BLK_FLOATS (NPB * T_STEPS)       // 6400 floats = 25.6 KB
#define TAIL_OFF (6 * BLOCK * 4)         // 6144: float tail offset

// Per-thread staging registers: 6 float4 + 1 float = 25 floats.
struct Stage {
  float4 v[6];
  float tail;
};

__device__ __forceinline__ void stage_load(const float* __restrict__ g,
                                           int tid, Stage& st) {
  const float4* g4 = reinterpret_cast<const float4*>(g);
#pragma unroll
  for (int it = 0; it < 6; ++it) st.v[it] = g4[it * BLOCK + tid];
  st.tail = g[TAIL_OFF + tid];
}

__device__ __forceinline__ void stage_write(float* lds, int tid,
                                            const Stage& st) {
  float4* l4 = reinterpret_cast<float4*>(lds);
#pragma unroll
  for (int it = 0; it < 6; ++it) l4[it * BLOCK + tid] = st.v[it];
  lds[TAIL_OFF + tid] = st.tail;
}

template <bool WRITE_PARTIAL>
__device__ __forceinline__ void block_body(const float* __restrict__ outputs,
                                           const float* __restrict__ target,
                                           float* __restrict__ partial,
                                           float* __restrict__ out) {
  __shared__ float buf[BLK_FLOATS];  // target, then reused for outputs
  __shared__ float wsum[BLOCK / 64];

  const int tid = threadIdx.x;
  const size_t base = (size_t)blockIdx.x * BLK_FLOATS;

  // ---- Phase A: stage target via VGPR (loads pipeline with ds_writes) ----
  Stage st;
  stage_load(target + base, tid, st);
  stage_write(buf, tid, st);
  __syncthreads();

  // ---- Phase B: pull row into registers ----
  // thread tid owns floats [25*tid, 25*tid+25): neuron n = tid>>2, seg s = tid&3.
  // Bank for fixed j: (25*tid+j)%32, gcd(25,32)=1 -> 2-way across 64 lanes -> free.
  const int s = tid & 3;
  const int rowoff = tid * SEG;
  float xr[SEG];
#pragma unroll
  for (int j = 0; j < SEG; ++j) xr[j] = buf[rowoff + j];

  // ---- Issue outputs loads NOW (latency hides under E-scan + barrier) ----
  stage_load(outputs + base, tid, st);

  // ---- E-scan + carry compose (identical chains to R5/R8) ----
  float E = 0.f;
#pragma unroll
  for (int j = 0; j < SEG; ++j) E = fmaf(E, 0.8f, xr[j]);

  const float A25 = 3.77789319e-3f;  // 0.8^25
  const float A50 = 1.42724769e-5f;  // 0.8^50
  const float e1 = __shfl_up(E, 1, 4);
  const float e2 = __shfl_up(E, 2, 4);
  const float e3 = __shfl_up(E, 3, 4);
  float carry = 0.f;
  if (s >= 1) carry = e1;
  if (s >= 2) carry = fmaf(A25, e2, carry);
  if (s >= 3) carry = fmaf(A50, e3, carry);

  __syncthreads();  // ALL waves finished reading x before buf is overwritten

  // ---- Phase A2: write outputs into the same buffer ----
  stage_write(buf, tid, st);
  __syncthreads();

  // ---- Phase C: fused rescan + compare (x from regs, outputs from LDS) ----
  float syn = carry;
  float acc = 0.f;
#pragma unroll
  for (int j = 0; j < SEG; ++j) {
    syn = fmaf(syn, 0.8f, xr[j]);
    float d = fmaf(-0.2f, syn, buf[rowoff + j]);
    acc = fmaf(d, d, acc);
  }

  // ---- block reduction (same tree as R5/R8) ----
#pragma unroll
  for (int off = 32; off > 0; off >>= 1) acc += __shfl_down(acc, off, 64);
  const int lane = tid & 63;
  const int wid = tid >> 6;
  if (lane == 0) wsum[wid] = acc;
  __syncthreads();
  const float blocksum = ((wsum[0] + wsum[1]) + wsum[2]) + wsum[3];

  if (tid == 0) {
    if (WRITE_PARTIAL) partial[blockIdx.x] = blocksum;
    else atomicAdd(out, 0.5f * blocksum);
  }
}

__global__ __launch_bounds__(BLOCK, 6) void spike_loss_partial(
    const float* __restrict__ outputs,
    const float* __restrict__ target,
    float* __restrict__ partial) {
  block_body<true>(outputs, target, partial, nullptr);
}

// Deterministic final reduction over per-block partials; applies the 0.5.
__global__ __launch_bounds__(256) void spike_loss_final(
    const float* __restrict__ partial, float* __restrict__ out, int nparts) {
  float acc = 0.0f;
  for (int i = threadIdx.x; i < nparts; i += 256) acc += partial[i];
#pragma unroll
  for (int off = 32; off > 0; off >>= 1) acc += __shfl_down(acc, off, 64);
  __shared__ float wsum[4];
  const int lane = threadIdx.x & 63;
  const int wid = threadIdx.x >> 6;
  if (lane == 0) wsum[wid] = acc;
  __syncthreads();
  if (threadIdx.x == 0) out[0] = 0.5f * (wsum[0] + wsum[1] + wsum[2] + wsum[3]);
}

// Fallback if d_ws is unusably small: atomic finish into d_out.
__global__ __launch_bounds__(BLOCK, 6) void spike_loss_atomic(
    const float* __restrict__ outputs,
    const float* __restrict__ target,
    float* __restrict__ out) {
  block_body<false>(outputs, target, nullptr, out);
}

extern "C" void kernel_launch(void* const* d_in, const int* in_sizes, int n_in,
                              void* d_out, int out_size, void* d_ws, size_t ws_size,
                              hipStream_t stream) {
  const float* outputs = (const float*)d_in[0];
  const float* target = (const float*)d_in[1];
  float* out = (float*)d_out;

  if (ws_size >= NPARTS * sizeof(float)) {
    float* partial = (float*)d_ws;
    spike_loss_partial<<<GRID_P, BLOCK, 0, stream>>>(outputs, target, partial);
    spike_loss_final<<<1, 256, 0, stream>>>(partial, out, NPARTS);
  } else {
    hipMemsetAsync(out, 0, sizeof(float), stream);
    spike_loss_atomic<<<GRID_P, BLOCK, 0, stream>>>(outputs, target, out);
  }
}

// Round 5
// 410.401 us; speedup vs baseline: 1.0582x; 1.0582x over previous
//
#include <hip/hip_runtime.h>

// SpikeLoss: loss = 0.5 * sum((outputs - psp(target))^2)
// psp: syn_t = syn_{t-1}*0.8 + x_t, emit syn_t/5   (tau=5)
// Shape [B=16, C=128, H=16, W=16, T=100], T contiguous. 524288 neurons.
//
// R10: R5/R6/R8 (all global_load_lds DMA) pinned at 1.58 TB/s HBM /
// ~3.2 TB/s delivered across occupancy 14->52% and three pipeline shapes.
// R9 (reg staging) accidentally proved the memory system does 3.5 TB/s HBM
// even while hauling 313 MB of scratch-spill traffic (Stage struct held
// across two barriers -> allocator spilled, VGPR=40 vs ~65 live).
// => The DMA path was the cap; the spill was R9's only real problem.
// R10 = R5's two-buffer structure, reg-staged, with NO live state across
// barriers: stage BOTH tensors up-front (transient regs only), one sync,
// then row-wise scan/compare. launch_bounds(256,3) -> ~170 VGPR cap, no
// allocator pressure. LDS 51.2 KB -> 3 blocks/CU (occupancy proven
// irrelevant in R8). Math chains / carry compose / reduce tree / partial
// layout bit-identical to R5/R8 -> absmax 0.0 preserved.

#define T_STEPS 100
#define SEG 25
#define NPB 64                           // neurons per block
#define BLOCK 256
#define N_NEURONS (16 * 128 * 16 * 16)   // 524288
#define GRID_P (N_NEURONS / NPB)         // 8192 blocks
#define NPARTS GRID_P                    // one partial per 64-neuron block
#define BLK_FLOATS (NPB * T_STEPS)       // 6400 floats = 25.6 KB per array
#define TAIL_OFF (6 * BLOCK * 4)         // 6144: float tail offset

// Stage one 6400-float array via VGPRs: 6x float4 + 1 float per thread.
// Called with nothing else live; loads hoist together (counted vmcnt
// pipelining), writes drain as returns arrive. ~28 transient VGPRs.
__device__ __forceinline__ void stage_reg(const float* __restrict__ g,
                                          float* lds, int tid) {
  const float4* g4 = reinterpret_cast<const float4*>(g);
  float4* l4 = reinterpret_cast<float4*>(lds);
  float4 v0 = g4[0 * BLOCK + tid];
  float4 v1 = g4[1 * BLOCK + tid];
  float4 v2 = g4[2 * BLOCK + tid];
  float4 v3 = g4[3 * BLOCK + tid];
  float4 v4 = g4[4 * BLOCK + tid];
  float4 v5 = g4[5 * BLOCK + tid];
  float vt = g[TAIL_OFF + tid];
  l4[0 * BLOCK + tid] = v0;
  l4[1 * BLOCK + tid] = v1;
  l4[2 * BLOCK + tid] = v2;
  l4[3 * BLOCK + tid] = v3;
  l4[4 * BLOCK + tid] = v4;
  l4[5 * BLOCK + tid] = v5;
  lds[TAIL_OFF + tid] = vt;
}

template <bool WRITE_PARTIAL>
__device__ __forceinline__ void block_body(const float* __restrict__ outputs,
                                           const float* __restrict__ target,
                                           float* __restrict__ partial,
                                           float* __restrict__ out) {
  __shared__ float bufX[BLK_FLOATS];  // target   — 25.6 KB
  __shared__ float bufO[BLK_FLOATS];  // outputs  — 25.6 KB
  __shared__ float wsum[BLOCK / 64];

  const int tid = threadIdx.x;
  const size_t base = (size_t)blockIdx.x * BLK_FLOATS;

  // ---- Phase A: stage both tensors via VGPR (transient regs only) ----
  stage_reg(target + base, bufX, tid);
  stage_reg(outputs + base, bufO, tid);
  __syncthreads();

  // ---- Phase B: row scan. thread tid owns floats [25*tid, 25*tid+25):
  // neuron n = tid>>2, segment s = tid&3. Bank for fixed j: (25*tid+j)%32,
  // gcd(25,32)=1 -> 2-way across 64 lanes -> conflict-free.
  const int s = tid & 3;
  const int rowoff = tid * SEG;
  float xr[SEG];
#pragma unroll
  for (int j = 0; j < SEG; ++j) xr[j] = bufX[rowoff + j];

  float E = 0.f;
#pragma unroll
  for (int j = 0; j < SEG; ++j) E = fmaf(E, 0.8f, xr[j]);

  // carry = syn at end of previous segments (exact compose, same as R5/R8)
  const float A25 = 3.77789319e-3f;  // 0.8^25
  const float A50 = 1.42724769e-5f;  // 0.8^50
  const float e1 = __shfl_up(E, 1, 4);
  const float e2 = __shfl_up(E, 2, 4);
  const float e3 = __shfl_up(E, 3, 4);
  float carry = 0.f;
  if (s >= 1) carry = e1;
  if (s >= 2) carry = fmaf(A25, e2, carry);
  if (s >= 3) carry = fmaf(A50, e3, carry);

  // ---- Phase C: fused rescan + compare (x from regs, outputs from LDS) ----
  float syn = carry;
  float acc = 0.f;
#pragma unroll
  for (int j = 0; j < SEG; ++j) {
    syn = fmaf(syn, 0.8f, xr[j]);
    float d = fmaf(-0.2f, syn, bufO[rowoff + j]);
    acc = fmaf(d, d, acc);
  }

  // ---- block reduction (same tree as R5/R8) ----
#pragma unroll
  for (int off = 32; off > 0; off >>= 1) acc += __shfl_down(acc, off, 64);
  const int lane = tid & 63;
  const int wid = tid >> 6;
  if (lane == 0) wsum[wid] = acc;
  __syncthreads();
  const float blocksum = ((wsum[0] + wsum[1]) + wsum[2]) + wsum[3];

  if (tid == 0) {
    if (WRITE_PARTIAL) partial[blockIdx.x] = blocksum;
    else atomicAdd(out, 0.5f * blocksum);
  }
}

__global__ __launch_bounds__(BLOCK, 3) void spike_loss_partial(
    const float* __restrict__ outputs,
    const float* __restrict__ target,
    float* __restrict__ partial) {
  block_body<true>(outputs, target, partial, nullptr);
}

// Deterministic final reduction over per-block partials; applies the 0.5.
__global__ __launch_bounds__(256) void spike_loss_final(
    const float* __restrict__ partial, float* __restrict__ out, int nparts) {
  float acc = 0.0f;
  for (int i = threadIdx.x; i < nparts; i += 256) acc += partial[i];
#pragma unroll
  for (int off = 32; off > 0; off >>= 1) acc += __shfl_down(acc, off, 64);
  __shared__ float wsum[4];
  const int lane = threadIdx.x & 63;
  const int wid = threadIdx.x >> 6;
  if (lane == 0) wsum[wid] = acc;
  __syncthreads();
  if (threadIdx.x == 0) out[0] = 0.5f * (wsum[0] + wsum[1] + wsum[2] + wsum[3]);
}

// Fallback if d_ws is unusably small: atomic finish into d_out.
__global__ __launch_bounds__(BLOCK, 3) void spike_loss_atomic(
    const float* __restrict__ outputs,
    const float* __restrict__ target,
    float* __restrict__ out) {
  block_body<false>(outputs, target, nullptr, out);
}

extern "C" void kernel_launch(void* const* d_in, const int* in_sizes, int n_in,
                              void* d_out, int out_size, void* d_ws, size_t ws_size,
                              hipStream_t stream) {
  const float* outputs = (const float*)d_in[0];
  const float* target = (const float*)d_in[1];
  float* out = (float*)d_out;

  if (ws_size >= NPARTS * sizeof(float)) {
    float* partial = (float*)d_ws;
    spike_loss_partial<<<GRID_P, BLOCK, 0, stream>>>(outputs, target, partial);
    spike_loss_final<<<1, 256, 0, stream>>>(partial, out, NPARTS);
  } else {
    hipMemsetAsync(out, 0, sizeof(float), stream);
    spike_loss_atomic<<<GRID_P, BLOCK, 0, stream>>>(outputs, target, out);
  }
}